// Round 1
// baseline (747.803 us; speedup 1.0000x reference)
//
#include <hip/hip_runtime.h>
#include <hip/hip_bf16.h>

#define BB 2
#define CC 128
#define HH 128
#define WW 128
#define ZZ 16
#define NG 4

__global__ __launch_bounds__(256) void normconv_kernel(
    const float* __restrict__ x,
    const float* __restrict__ w0,
    const float* __restrict__ w1,
    float* __restrict__ out)
{
    __shared__ float sw[2][27];

    const int c = blockIdx.y;
    const int b = blockIdx.z;
    const int g = c & 3;
    const int tid = threadIdx.x;

    // ---- softmax of this group's two 3x3x3 kernels (first wave only) ----
    if (tid < 64) {
        const int s = tid >> 5;        // 0 -> w0, 1 -> w1
        const int k = tid & 31;        // weight index within kernel
        const float* wsrc = s ? w1 : w0;
        float v = (k < 27) ? wsrc[g * 27 + k] : -3.4e38f;
        float m = v;
        #pragma unroll
        for (int off = 16; off; off >>= 1) m = fmaxf(m, __shfl_xor(m, off, 32));
        float e = (k < 27) ? __expf(v - m) : 0.f;
        float ssum = e;
        #pragma unroll
        for (int off = 16; off; off >>= 1) ssum += __shfl_xor(ssum, off, 32);
        if (k < 27) sw[s][k] = e / ssum;
    }
    __syncthreads();

    // ---- per-thread output column ----
    const int ty = tid >> 4;
    const int tx = tid & 15;
    const int h = ((blockIdx.x >> 3) << 4) + ty;
    const int w = ((blockIdx.x & 7) << 4) + tx;

    const float* xc = x + ((size_t)b * CC + c) * (size_t)(HH * WW * ZZ);

    float acc[ZZ];
    #pragma unroll
    for (int z = 0; z < ZZ; ++z) acc[z] = 0.f;

    float col[ZZ + 4];
    col[0] = col[1] = col[ZZ + 2] = col[ZZ + 3] = 0.f;

    auto loadcol = [&](int hh, int ww) {
        if (hh < 0 || hh >= HH || ww < 0 || ww >= WW) {
            #pragma unroll
            for (int z = 0; z < ZZ; ++z) col[z + 2] = 0.f;
        } else {
            const float4* p = (const float4*)(xc + ((size_t)hh * WW + ww) * ZZ);
            #pragma unroll
            for (int q = 0; q < 4; ++q) {
                float4 v = p[q];
                col[2 + q * 4 + 0] = v.x;
                col[2 + q * 4 + 1] = v.y;
                col[2 + q * 4 + 2] = v.z;
                col[2 + q * 4 + 3] = v.w;
            }
        }
    };

    #pragma unroll
    for (int dh = -2; dh <= 2; ++dh) {
        #pragma unroll
        for (int dw = -2; dw <= 2; ++dw) {
            const bool use1 = (dh >= -1) && (dh <= 1) && (dw >= -1) && (dw <= 1);
            const bool use2 = (((dh & 1) == 0) && ((dw & 1) == 0));
            if (!use1 && !use2) continue;

            loadcol(h + dh, w + dw);

            if (dh == 0 && dw == 0) {
                // identity term
                #pragma unroll
                for (int z = 0; z < ZZ; ++z) acc[z] += col[z + 2];
            }
            if (use1) {
                const int base = ((dh + 1) * 3 + (dw + 1)) * 3;
                const float a0 = sw[0][base + 0];
                const float a1 = sw[0][base + 1];
                const float a2 = sw[0][base + 2];
                #pragma unroll
                for (int z = 0; z < ZZ; ++z)
                    acc[z] += a0 * col[z + 1] + a1 * col[z + 2] + a2 * col[z + 3];
            }
            if (use2) {
                const int base = (((dh >> 1) + 1) * 3 + ((dw >> 1) + 1)) * 3;
                const float b0 = sw[1][base + 0];
                const float b1 = sw[1][base + 1];
                const float b2 = sw[1][base + 2];
                #pragma unroll
                for (int z = 0; z < ZZ; ++z)
                    acc[z] += b0 * col[z + 0] + b1 * col[z + 2] + b2 * col[z + 4];
            }
        }
    }

    // ---- store with channel shuffle folded in: cc = (c%4)*32 + c/4 ----
    const int cshuf = ((c & 3) << 5) | (c >> 2);
    const float inv3 = 1.f / 3.f;
    float4* po = (float4*)(out + (((size_t)b * CC + cshuf) * (size_t)HH * WW
                                  + (size_t)h * WW + w) * ZZ);
    #pragma unroll
    for (int q = 0; q < 4; ++q) {
        float4 v;
        v.x = acc[q * 4 + 0] * inv3;
        v.y = acc[q * 4 + 1] * inv3;
        v.z = acc[q * 4 + 2] * inv3;
        v.w = acc[q * 4 + 3] * inv3;
        po[q] = v;
    }
}

extern "C" void kernel_launch(void* const* d_in, const int* in_sizes, int n_in,
                              void* d_out, int out_size, void* d_ws, size_t ws_size,
                              hipStream_t stream) {
    const float* x  = (const float*)d_in[0];
    const float* w0 = (const float*)d_in[1];
    const float* w1 = (const float*)d_in[2];
    float* out = (float*)d_out;

    dim3 grid(64, CC, BB);   // 8x8 (h,w) tiles, channels, batch
    dim3 block(256);
    normconv_kernel<<<grid, block, 0, stream>>>(x, w0, w1, out);
}